// Round 1
// baseline (5346.633 us; speedup 1.0000x reference)
//
#include <hip/hip_runtime.h>
#include <math.h>

#define TAGS 9

static __device__ __forceinline__ float sigmoidf_(float x) {
  return 1.0f / (1.0f + expf(-x));
}

// ---------------- transpose w_hh: [4][1024][256] -> [4][256][1024] ----------------
__global__ void k_transpose_whh(const float* __restrict__ whh, float* __restrict__ whhT) {
  __shared__ float tile[64][65];
  int bid = blockIdx.x;            // 4 slices * 16 r-tiles * 4 k-tiles = 256
  int ld = bid >> 6;
  int rt = (bid >> 2) & 15;
  int kt = bid & 3;
  const float* in = whh + (size_t)ld * 1024 * 256;
  float* out = whhT + (size_t)ld * 256 * 1024;
  int tid = threadIdx.x;
  int lr = tid >> 6;               // 0..3
  int lc = tid & 63;               // 0..63
#pragma unroll
  for (int i = 0; i < 16; i++) {
    int r = rt * 64 + i * 4 + lr;
    tile[lc][i * 4 + lr] = in[(size_t)r * 256 + kt * 64 + lc];
  }
  __syncthreads();
#pragma unroll
  for (int i = 0; i < 16; i++) {
    int k = kt * 64 + i * 4 + lr;
    out[(size_t)k * 1024 + rt * 64 + lc] = tile[i * 4 + lr][lc];
  }
}

// ---------------- embedding gather: seq[tb][e] = table[x[tb]][e] ----------------
__global__ void k_gather(const int* __restrict__ x, const float* __restrict__ table,
                         float* __restrict__ seq) {
  int tid = blockIdx.x * 256 + threadIdx.x;   // 16384*128 float4s
  int row = tid >> 7;
  int e4 = tid & 127;
  int idx = x[row];
  const float4* src = (const float4*)(table + (size_t)idx * 512);
  float4* dst = (float4*)(seq + (size_t)row * 512);
  dst[e4] = src[e4];
}

// ---------------- fp32 NT GEMM: C[M,N] = A[M,K] @ W[N,K]^T + bias1[n]+bias2[n] ----------------
// BM=BN=128, BK=16, 256 threads, 8x8 per thread (split 4+4 to keep LDS reads 2-way max)
__global__ __launch_bounds__(256, 2)
void k_gemm_nt(const float* __restrict__ A, const float* __restrict__ W,
               const float* __restrict__ bias1, const float* __restrict__ bias2,
               float* __restrict__ C, int M, int N, int K) {
  __shared__ float As[16][132];
  __shared__ float Ws[16][132];
  int tid = threadIdx.x;
  int tx = tid & 15, ty = tid >> 4;
  int n0 = blockIdx.x * 128, m0 = blockIdx.y * 128;
  int lr = tid >> 2;               // 0..63
  int lk = (tid & 3) * 4;          // 0,4,8,12
  float acc[8][8];
#pragma unroll
  for (int i = 0; i < 8; i++)
#pragma unroll
    for (int j = 0; j < 8; j++) acc[i][j] = 0.f;
  const float* Ab = A + (size_t)m0 * K;
  const float* Wb = W + (size_t)n0 * K;
  for (int k0 = 0; k0 < K; k0 += 16) {
    float4 a0 = *(const float4*)&Ab[(size_t)lr * K + k0 + lk];
    float4 a1 = *(const float4*)&Ab[(size_t)(lr + 64) * K + k0 + lk];
    float4 w0 = *(const float4*)&Wb[(size_t)lr * K + k0 + lk];
    float4 w1 = *(const float4*)&Wb[(size_t)(lr + 64) * K + k0 + lk];
    __syncthreads();
    As[lk + 0][lr] = a0.x; As[lk + 1][lr] = a0.y; As[lk + 2][lr] = a0.z; As[lk + 3][lr] = a0.w;
    As[lk + 0][lr + 64] = a1.x; As[lk + 1][lr + 64] = a1.y; As[lk + 2][lr + 64] = a1.z; As[lk + 3][lr + 64] = a1.w;
    Ws[lk + 0][lr] = w0.x; Ws[lk + 1][lr] = w0.y; Ws[lk + 2][lr] = w0.z; Ws[lk + 3][lr] = w0.w;
    Ws[lk + 0][lr + 64] = w1.x; Ws[lk + 1][lr + 64] = w1.y; Ws[lk + 2][lr + 64] = w1.z; Ws[lk + 3][lr + 64] = w1.w;
    __syncthreads();
#pragma unroll
    for (int kk = 0; kk < 16; kk++) {
      float4 av0 = *(const float4*)&As[kk][ty * 4];
      float4 av1 = *(const float4*)&As[kk][ty * 4 + 64];
      float4 wv0 = *(const float4*)&Ws[kk][tx * 4];
      float4 wv1 = *(const float4*)&Ws[kk][tx * 4 + 64];
      float am[8] = {av0.x, av0.y, av0.z, av0.w, av1.x, av1.y, av1.z, av1.w};
      float wn[8] = {wv0.x, wv0.y, wv0.z, wv0.w, wv1.x, wv1.y, wv1.z, wv1.w};
#pragma unroll
      for (int i = 0; i < 8; i++)
#pragma unroll
        for (int j = 0; j < 8; j++) acc[i][j] += am[i] * wn[j];
    }
  }
  float bsum[8];
#pragma unroll
  for (int j = 0; j < 8; j++) {
    int n = n0 + ((j < 4) ? (tx * 4 + j) : (64 + tx * 4 + (j - 4)));
    bsum[j] = bias1[n] + bias2[n];
  }
#pragma unroll
  for (int i = 0; i < 8; i++) {
    int m = m0 + ((i < 4) ? (ty * 4 + i) : (64 + ty * 4 + (i - 4)));
    float4 o0 = {acc[i][0] + bsum[0], acc[i][1] + bsum[1], acc[i][2] + bsum[2], acc[i][3] + bsum[3]};
    float4 o1 = {acc[i][4] + bsum[4], acc[i][5] + bsum[5], acc[i][6] + bsum[6], acc[i][7] + bsum[7]};
    *(float4*)&C[(size_t)m * N + n0 + tx * 4] = o0;
    *(float4*)&C[(size_t)m * N + n0 + 64 + tx * 4] = o1;
  }
}

// ---------------- LSTM recurrence, one layer, both dirs ----------------
// grid 64 = (dir, batch-pair); 512 threads: phase B identity (kh = tid>>8 k-half, j = tid&255
// owning gate rows 4j..4j+3); phase C identity (bs = tid>>8 batch, u = tid&255 hidden unit).
#define FMA4(ACC, WV, S) { ACC.x += WV.x * (S); ACC.y += WV.y * (S); ACC.z += WV.z * (S); ACC.w += WV.w * (S); }
__global__ __launch_bounds__(512, 1)
void k_lstm(const float* __restrict__ gates_in,  // [T*64][2048] (dir-major cols)
            const float* __restrict__ whhT2,     // [2][256][1024] for this layer
            float* __restrict__ seq_out) {       // [T*64][512]
  int wg = blockIdx.x;
  int dir = wg & 1;
  int b0 = (wg >> 1) * 2;
  const float* wT = whhT2 + (size_t)dir * 256 * 1024;
  int tid = threadIdx.x;
  int kh = tid >> 8;
  int j4 = (tid & 255) * 4;
  int bs = kh, u = tid & 255;
  __shared__ float h_lds[2][256];
  __shared__ float part[2][2][1024];
  h_lds[kh][u] = 0.f;
  float c = 0.f;
  __syncthreads();
  const int khbase = kh * 128;
  const float* wbase = wT + (size_t)khbase * 1024 + j4;
  for (int tt = 0; tt < 256; tt++) {
    int t = dir ? (255 - tt) : tt;
    float4 acc0, acc1;
    if (kh == 0) {
      const float* gi = gates_in + (size_t)(t * 64 + b0) * 2048 + dir * 1024 + j4;
      acc0 = *(const float4*)gi;
      acc1 = *(const float4*)(gi + 2048);
    } else {
      acc0 = float4{0.f, 0.f, 0.f, 0.f};
      acc1 = float4{0.f, 0.f, 0.f, 0.f};
    }
#pragma unroll 4
    for (int k = 0; k < 128; k += 4) {
      float4 ha = *(const float4*)&h_lds[0][khbase + k];
      float4 hb = *(const float4*)&h_lds[1][khbase + k];
      const float* w = wbase + (size_t)k * 1024;
      float4 w0 = *(const float4*)(w);
      float4 w1 = *(const float4*)(w + 1024);
      float4 w2 = *(const float4*)(w + 2048);
      float4 w3 = *(const float4*)(w + 3072);
      FMA4(acc0, w0, ha.x) FMA4(acc0, w1, ha.y) FMA4(acc0, w2, ha.z) FMA4(acc0, w3, ha.w)
      FMA4(acc1, w0, hb.x) FMA4(acc1, w1, hb.y) FMA4(acc1, w2, hb.z) FMA4(acc1, w3, hb.w)
    }
    *(float4*)&part[kh][0][j4] = acc0;
    *(float4*)&part[kh][1][j4] = acc1;
    __syncthreads();
    // phase C: pointwise for (batch bs, unit u); gate rows i=u, f=256+u, g=512+u, o=768+u
    float gi_ = part[0][bs][u]       + part[1][bs][u];
    float gf  = part[0][bs][256 + u] + part[1][bs][256 + u];
    float gg  = part[0][bs][512 + u] + part[1][bs][512 + u];
    float go  = part[0][bs][768 + u] + part[1][bs][768 + u];
    c = sigmoidf_(gf) * c + sigmoidf_(gi_) * tanhf(gg);
    float h = sigmoidf_(go) * tanhf(c);
    h_lds[bs][u] = h;
    seq_out[(size_t)(t * 64 + b0 + bs) * 512 + dir * 256 + u] = h;
    __syncthreads();
  }
}

// ---------------- emissions: em[tb][tag] = seq[tb]·out_w[tag] + out_b[tag] ----------------
__global__ void k_emis(const float* __restrict__ seq, const float* __restrict__ out_w,
                       const float* __restrict__ out_b, float* __restrict__ em) {
  __shared__ float ow[TAGS * 512];
  int tid = threadIdx.x;
  for (int i = tid; i < TAGS * 512; i += 256) ow[i] = out_w[i];
  __syncthreads();
  int lane = tid & 63;
  int row = blockIdx.x * 4 + (tid >> 6);
  const float* s = seq + (size_t)row * 512;
  float p[TAGS];
#pragma unroll
  for (int t = 0; t < TAGS; t++) p[t] = 0.f;
#pragma unroll
  for (int kk = 0; kk < 8; kk++) {
    float sv = s[lane + kk * 64];
#pragma unroll
    for (int t = 0; t < TAGS; t++) p[t] += sv * ow[t * 512 + lane + kk * 64];
  }
#pragma unroll
  for (int t = 0; t < TAGS; t++) {
    float v = p[t];
#pragma unroll
    for (int off = 32; off > 0; off >>= 1) v += __shfl_down(v, off, 64);
    if (lane == 0) em[(size_t)row * TAGS + t] = v + out_b[t];
  }
}

// ---------------- Viterbi: one wave per batch ----------------
__global__ void k_viterbi(const float* __restrict__ em, const float* __restrict__ start_t,
                          const float* __restrict__ end_t, const float* __restrict__ trans,
                          float* __restrict__ out) {
  int b = blockIdx.x;
  int lane = threadIdx.x;   // 64 threads, lanes 0..8 active for tags
  __shared__ unsigned char hist[255 * TAGS];
  float tin[TAGS];
#pragma unroll
  for (int p = 0; p < TAGS; p++) tin[p] = (lane < TAGS) ? trans[p * TAGS + lane] : 0.f;
  float score = -1e30f;
  if (lane < TAGS) score = start_t[lane] + em[(size_t)b * TAGS + lane];
  for (int t = 1; t < 256; t++) {
    float best = -1e30f; int bp = 0;
#pragma unroll
    for (int p = 0; p < TAGS; p++) {
      float v = __shfl(score, p, 64) + tin[p];
      if (v > best) { best = v; bp = p; }   // strict > + ascending p == first-max (jnp.argmax)
    }
    if (lane < TAGS) {
      score = best + em[(size_t)(t * 64 + b) * TAGS + lane];
      hist[(t - 1) * TAGS + lane] = (unsigned char)bp;
    }
  }
  float fin = (lane < TAGS) ? (score + end_t[lane]) : -1e30f;
  float bsc = -1e30f; int bl = 0;
#pragma unroll
  for (int p = 0; p < TAGS; p++) {
    float v = __shfl(fin, p, 64);
    if (v > bsc) { bsc = v; bl = p; }
  }
  __syncthreads();
  if (lane == 0) {
    out[(size_t)16384 + b] = bsc;          // best_score[b]
    int tag = bl;
    out[(size_t)b * 256 + 255] = (float)tag;
    for (int t = 254; t >= 0; t--) {
      tag = hist[t * TAGS + tag];
      out[(size_t)b * 256 + t] = (float)tag;
    }
  }
}

extern "C" void kernel_launch(void* const* d_in, const int* in_sizes, int n_in,
                              void* d_out, int out_size, void* d_ws, size_t ws_size,
                              hipStream_t stream) {
  const int*   x       = (const int*)d_in[0];
  const float* table   = (const float*)d_in[1];
  const float* w_ih    = (const float*)d_in[2];   // [2][2][1024][512]
  const float* w_hh    = (const float*)d_in[3];   // [2][2][1024][256]
  const float* b_ih    = (const float*)d_in[4];   // [2][2][1024]
  const float* b_hh    = (const float*)d_in[5];
  const float* out_w   = (const float*)d_in[6];   // [9][512]
  const float* out_b   = (const float*)d_in[7];
  const float* start_t = (const float*)d_in[8];
  const float* end_t   = (const float*)d_in[9];
  const float* trans   = (const float*)d_in[10];  // [9][9]
  float* out = (float*)d_out;
  float* ws = (float*)d_ws;

  float* whhT  = ws;                      // 4*256*1024      = 1,048,576 floats
  float* seq0  = whhT + 1048576;          // 16384*512       = 8,388,608 (embeds, later layer-2 out)
  float* seq1  = seq0 + 8388608;          // 16384*512       (layer-1 out)
  float* gates = seq1 + 8388608;          // 16384*2048      = 33,554,432
  float* em    = gates + 33554432;        // 16384*9         = 147,456
  // total ~206 MB

  k_transpose_whh<<<256, 256, 0, stream>>>(w_hh, whhT);
  k_gather<<<8192, 256, 0, stream>>>(x, table, seq0);

  dim3 gg(16, 128);
  // layer 0
  k_gemm_nt<<<gg, 256, 0, stream>>>(seq0, w_ih, b_ih, b_hh, gates, 16384, 2048, 512);
  k_lstm<<<64, 512, 0, stream>>>(gates, whhT, seq1);
  // layer 1
  k_gemm_nt<<<gg, 256, 0, stream>>>(seq1, w_ih + 1048576, b_ih + 2048, b_hh + 2048, gates, 16384, 2048, 512);
  k_lstm<<<64, 512, 0, stream>>>(gates, whhT + 524288, seq0);
  // emissions + viterbi
  k_emis<<<4096, 256, 0, stream>>>(seq0, out_w, out_b, em);
  k_viterbi<<<64, 64, 0, stream>>>(em, start_t, end_t, trans, out);
}